// Round 9
// baseline (112.339 us; speedup 1.0000x reference)
//
#include <hip/hip_runtime.h>
#include <math.h>

#define DIM 96
#define NE 4
#define HH 128
#define WW 128
#define BB 16
#define HSROW 48                 // bytes per px row: 16 ch bf16 (32 B) + 16 B pad
#define HSBUF (256 * HSROW)      // 12 KB per sub-buffer (256 px = 2 image rows)
#define PWROW 192                // bytes per pwb row (96 k bf16)

typedef __attribute__((ext_vector_type(8))) __bf16 bf16x8;
typedef __attribute__((ext_vector_type(4))) float floatx4;

__device__ __forceinline__ unsigned short f2bf(float f) {
    unsigned u = __builtin_bit_cast(unsigned, f);
    unsigned r = u + 0x7FFFu + ((u >> 16) & 1u);   // RNE
    return (unsigned short)(r >> 16);
}
__device__ __forceinline__ unsigned pack2(float a, float b) {
    return (unsigned)f2bf(a) | ((unsigned)f2bf(b) << 16);
}

// exact-erf GELU via Abramowitz-Stegun 7.1.26 (|eps| <= 1.5e-7), branchless
__device__ __forceinline__ float gelu_erf(float h) {
    const float x = h * 0.70710678118654752f;
    const float a = fabsf(x);
    const float t = __builtin_amdgcn_rcpf(__builtin_fmaf(0.3275911f, a, 1.0f));
    float p = __builtin_fmaf(1.061405429f, t, -1.453152027f);
    p = __builtin_fmaf(p, t, 1.421413741f);
    p = __builtin_fmaf(p, t, -0.284496736f);
    p = __builtin_fmaf(p, t, 0.254829592f);
    p *= t;
    const float e = __expf(-x * x);
    float erfv = __builtin_fmaf(-p, e, 1.0f);
    erfv = copysignf(erfv, x);
    return 0.5f * h * (1.0f + erfv);
}

// ---------------- Kernel A: per-(b,c) mean pool ----------------
__global__ __launch_bounds__(256) void pool_kernel(const float* __restrict__ x,
                                                   float* __restrict__ pooled) {
    const int bc = blockIdx.x;
    const float4* p = (const float4*)(x + (size_t)bc * (HH * WW));
    const int t = threadIdx.x;
    float s = 0.f;
#pragma unroll
    for (int k = 0; k < (HH * WW / 4) / 256; ++k) {
        float4 v = p[t + k * 256];
        s += v.x + v.y + v.z + v.w;
    }
#pragma unroll
    for (int off = 32; off; off >>= 1) s += __shfl_down(s, off, 64);
    __shared__ float ls[4];
    if ((t & 63) == 0) ls[t >> 6] = s;
    __syncthreads();
    if (t == 0) pooled[bc] = (ls[0] + ls[1] + ls[2] + ls[3]) * (1.0f / (HH * WW));
}

// ---------------- Kernel B: router ----------------
__global__ void router_kernel(const float* __restrict__ pooled,
                              const float* __restrict__ rw,
                              const float* __restrict__ rb,
                              float* __restrict__ gate, int* __restrict__ sel) {
    const int b = threadIdx.x;
    if (b >= BB) return;
    float logits[NE];
#pragma unroll
    for (int e = 0; e < NE; ++e) {
        float s = rb[e];
        for (int c = 0; c < DIM; ++c) s += pooled[b * DIM + c] * rw[e * DIM + c];
        logits[e] = s;
    }
    float m = logits[0];
    int mi = 0;
#pragma unroll
    for (int e = 1; e < NE; ++e)
        if (logits[e] > m) { m = logits[e]; mi = e; }
    float denom = 0.f;
#pragma unroll
    for (int e = 0; e < NE; ++e) denom += expf(logits[e] - m);
    float w = 1.0f / denom;
    gate[b] = w / (w + 1e-8f);
    sel[b] = mi;
}

// issue 8 float4 loads (2 ch x 4 input rows) for one 16-ch sub-chunk
__device__ __forceinline__ void issue_sub2(const float* __restrict__ x, int b,
                                           int cbase, int cg, int rm1, int r0,
                                           int rp2, int p4, float4 f[2][4]) {
#pragma unroll
    for (int u = 0; u < 2; ++u) {
        const float* pl = x + (size_t)(b * DIM + cbase + cg * 2 + u) * (HH * WW);
        f[u][0] = *(const float4*)(pl + rm1 * WW + p4);
        f[u][1] = *(const float4*)(pl + r0 * WW + p4);
        f[u][2] = *(const float4*)(pl + (r0 + 1) * WW + p4);
        f[u][3] = *(const float4*)(pl + rp2 * WW + p4);
    }
}

// depthwise 3x3 + GELU for 2 output rows from preloaded regs -> swizzled hs
__device__ __forceinline__ void compute_sub2(const float4 f[2][4],
                                             const float (*dwc)[12], int cb,
                                             int cg, float lmask, float rmask,
                                             float mTop, float mBot,
                                             unsigned char* hsbuf, int p4,
                                             unsigned swz) {
    float hA[2][4], hB[2][4];
#pragma unroll
    for (int u = 0; u < 2; ++u) {
        const int c = cb + cg * 2 + u;
        const float4 wA = *(const float4*)&dwc[c][0];   // t0..t3
        const float4 wB = *(const float4*)&dwc[c][4];   // t4..t7
        const float4 wC = *(const float4*)&dwc[c][8];   // t8, bias
        const float bs = wC.y;
        float vl[4], vr[4];
#pragma unroll
        for (int k = 0; k < 4; ++k) {
            vl[k] = __shfl_up(f[u][k].w, 1, 32) * lmask;
            vr[k] = __shfl_down(f[u][k].x, 1, 32) * rmask;
        }
        float a0 = bs, a1 = bs, a2 = bs, a3 = bs;
        float b0 = bs, b1 = bs, b2 = bs, b3 = bs;
        {   // input row r0-1 (masked): row A taps t0..t2
            const float ta = wA.x * mTop, tb = wA.y * mTop, tc = wA.z * mTop;
            const float4 q = f[u][0];
            a0 = __builtin_fmaf(ta, vl[0], __builtin_fmaf(tb, q.x, __builtin_fmaf(tc, q.y, a0)));
            a1 = __builtin_fmaf(ta, q.x, __builtin_fmaf(tb, q.y, __builtin_fmaf(tc, q.z, a1)));
            a2 = __builtin_fmaf(ta, q.y, __builtin_fmaf(tb, q.z, __builtin_fmaf(tc, q.w, a2)));
            a3 = __builtin_fmaf(ta, q.z, __builtin_fmaf(tb, q.w, __builtin_fmaf(tc, vr[0], a3)));
        }
        {   // input row r0: row A taps t3..t5, row B taps t0..t2
            const float4 q = f[u][1];
            a0 = __builtin_fmaf(wA.w, vl[1], __builtin_fmaf(wB.x, q.x, __builtin_fmaf(wB.y, q.y, a0)));
            a1 = __builtin_fmaf(wA.w, q.x, __builtin_fmaf(wB.x, q.y, __builtin_fmaf(wB.y, q.z, a1)));
            a2 = __builtin_fmaf(wA.w, q.y, __builtin_fmaf(wB.x, q.z, __builtin_fmaf(wB.y, q.w, a2)));
            a3 = __builtin_fmaf(wA.w, q.z, __builtin_fmaf(wB.x, q.w, __builtin_fmaf(wB.y, vr[1], a3)));
            b0 = __builtin_fmaf(wA.x, vl[1], __builtin_fmaf(wA.y, q.x, __builtin_fmaf(wA.z, q.y, b0)));
            b1 = __builtin_fmaf(wA.x, q.x, __builtin_fmaf(wA.y, q.y, __builtin_fmaf(wA.z, q.z, b1)));
            b2 = __builtin_fmaf(wA.x, q.y, __builtin_fmaf(wA.y, q.z, __builtin_fmaf(wA.z, q.w, b2)));
            b3 = __builtin_fmaf(wA.x, q.z, __builtin_fmaf(wA.y, q.w, __builtin_fmaf(wA.z, vr[1], b3)));
        }
        {   // input row r0+1: row A taps t6..t8, row B taps t3..t5
            const float4 q = f[u][2];
            a0 = __builtin_fmaf(wB.z, vl[2], __builtin_fmaf(wB.w, q.x, __builtin_fmaf(wC.x, q.y, a0)));
            a1 = __builtin_fmaf(wB.z, q.x, __builtin_fmaf(wB.w, q.y, __builtin_fmaf(wC.x, q.z, a1)));
            a2 = __builtin_fmaf(wB.z, q.y, __builtin_fmaf(wB.w, q.z, __builtin_fmaf(wC.x, q.w, a2)));
            a3 = __builtin_fmaf(wB.z, q.z, __builtin_fmaf(wB.w, q.w, __builtin_fmaf(wC.x, vr[2], a3)));
            b0 = __builtin_fmaf(wA.w, vl[2], __builtin_fmaf(wB.x, q.x, __builtin_fmaf(wB.y, q.y, b0)));
            b1 = __builtin_fmaf(wA.w, q.x, __builtin_fmaf(wB.x, q.y, __builtin_fmaf(wB.y, q.z, b1)));
            b2 = __builtin_fmaf(wA.w, q.y, __builtin_fmaf(wB.x, q.z, __builtin_fmaf(wB.y, q.w, b2)));
            b3 = __builtin_fmaf(wA.w, q.z, __builtin_fmaf(wB.x, q.w, __builtin_fmaf(wB.y, vr[2], b3)));
        }
        {   // input row r0+2 (masked): row B taps t6..t8
            const float ta = wB.z * mBot, tb = wB.w * mBot, tc = wC.x * mBot;
            const float4 q = f[u][3];
            b0 = __builtin_fmaf(ta, vl[3], __builtin_fmaf(tb, q.x, __builtin_fmaf(tc, q.y, b0)));
            b1 = __builtin_fmaf(ta, q.x, __builtin_fmaf(tb, q.y, __builtin_fmaf(tc, q.z, b1)));
            b2 = __builtin_fmaf(ta, q.y, __builtin_fmaf(tb, q.z, __builtin_fmaf(tc, q.w, b2)));
            b3 = __builtin_fmaf(ta, q.z, __builtin_fmaf(tb, q.w, __builtin_fmaf(tc, vr[3], b3)));
        }
        hA[u][0] = gelu_erf(a0); hA[u][1] = gelu_erf(a1);
        hA[u][2] = gelu_erf(a2); hA[u][3] = gelu_erf(a3);
        hB[u][0] = gelu_erf(b0); hB[u][1] = gelu_erf(b1);
        hB[u][2] = gelu_erf(b2); hB[u][3] = gelu_erf(b3);
    }
    const unsigned wbA = (unsigned)(p4 * HSROW + cg * 4);
    const unsigned wbB = wbA + 128u * HSROW;
#pragma unroll
    for (int j = 0; j < 4; ++j) {
        *(unsigned*)(hsbuf + ((wbA + (unsigned)j * HSROW) ^ swz)) =
            pack2(hA[0][j], hA[1][j]);
        *(unsigned*)(hsbuf + ((wbB + (unsigned)j * HSROW) ^ swz)) =
            pack2(hB[0][j], hB[1][j]);
    }
}

// ---------------- Kernel C: fused expert, 2 rows per block ----------------
// 256 threads = 4 waves (2 co-halves x 2 px-halves of 128). pw^T staged once;
// hs = 2 sub-buffers of 256 px; 2 barriers per 32-ch pair (6 total). Loads
// prefetched one pair ahead. XCD row-band swizzle for halo L2 locality.
__global__ __launch_bounds__(256, 3) void moe_main(
    const float* __restrict__ x, const float* __restrict__ dw_w,
    const float* __restrict__ dw_b, const float* __restrict__ pw_w,
    const float* __restrict__ pw_b, const float* __restrict__ gate,
    const int* __restrict__ sel, float* __restrict__ out) {
    __shared__ __align__(16) unsigned char pwb[DIM * PWROW];   // 18 KB
    __shared__ __align__(16) unsigned char hsb[2 * HSBUF];     // 24 KB
    __shared__ float dwc[DIM][12];                             // 4.6 KB

    const int t = threadIdx.x;
    const unsigned bid = blockIdx.x;      // 0..1023
    const int xcd = bid & 7;
    const int s = bid >> 3;               // 0..127
    const int b = s & 15;                 // b-fastest within an XCD band
    const int strip = xcd * 8 + (s >> 4); // 8 strips (16 rows) per XCD
    const int r0 = strip * 2;
    const int e = sel[b];
    const float g = gate[b];

    const int lane = t & 63, w = t >> 6;
    const int wm = w & 1, wn = w >> 1;
    const int ln = lane & 15, kg = lane >> 4;
    const int cobase = wm * 48, pxbase = wn * 128;

    const int g32 = t & 31;        // px group (4 px each)
    const int p4 = g32 * 4;
    const int cg = t >> 5;         // 0..7 channel group (2 ch each)
    const unsigned swz = (unsigned)((g32 & 7) << 4);
    const float lmask = (p4 == 0) ? 0.f : 1.f;
    const float rmask = (p4 == 124) ? 0.f : 1.f;

    const float mTop = (r0 > 0) ? 1.f : 0.f;
    const float mBot = (r0 < HH - 2) ? 1.f : 0.f;
    const int rm1 = (r0 > 0) ? r0 - 1 : 0;
    const int rp2 = (r0 < HH - 2) ? r0 + 2 : HH - 1;

    // prologue: issue pair-0 loads before weight staging
    float4 fA[2][4], fB[2][4];
    issue_sub2(x, b, 0, cg, rm1, r0, rp2, p4, fA);
    issue_sub2(x, b, 16, cg, rm1, r0, rp2, p4, fB);

    // ---- stage pw^T once: [co][96 k] bf16, 192 B rows, XOR (co&7)<<4
#pragma unroll
    for (int i = 0; i < 18; ++i) {
        const int u = i * 256 + t;               // 0..4607 dword slots
        const int co = u / 48, kp = u - co * 48;
        const float2 v = *(const float2*)(pw_w +
            ((size_t)e * DIM + co) * DIM + kp * 2);
        *(unsigned*)(pwb + ((unsigned)(co * PWROW + kp * 4) ^
                            (unsigned)((co & 7) << 4))) = pack2(v.x, v.y);
    }
    // ---- stage raw depthwise taps + bias (no mask folding; 2 rows differ)
    for (int j = t; j < DIM * 12; j += 256) {
        const int c = j / 12, q = j - c * 12;
        float v = 0.f;
        if (q < 9) v = dw_w[((size_t)e * DIM + c) * 9 + q];
        else if (q == 9) v = dw_b[e * DIM + c];
        dwc[c][q] = v;
    }
    __syncthreads();

    floatx4 acc[3][8];
#pragma unroll
    for (int i = 0; i < 3; ++i)
#pragma unroll
        for (int j = 0; j < 8; ++j) acc[i][j] = (floatx4){0.f, 0.f, 0.f, 0.f};

#pragma unroll
    for (int pair = 0; pair < 3; ++pair) {
        const int cb = pair * 32;
        // compute sub0/sub1 from in-flight regs; refill one pair ahead
        compute_sub2(fA, dwc, cb, cg, lmask, rmask, mTop, mBot, hsb, p4, swz);
        if (pair < 2) issue_sub2(x, b, cb + 32, cg, rm1, r0, rp2, p4, fA);
        compute_sub2(fB, dwc, cb + 16, cg, lmask, rmask, mTop, mBot,
                     hsb + HSBUF, p4, swz);
        if (pair < 2) issue_sub2(x, b, cb + 48, cg, rm1, r0, rp2, p4, fB);
        __syncthreads();

        // MFMA: K=32; kg>>1 picks sub-buffer, kg&1 picks 16B half-row
        const unsigned qbase = (unsigned)(kg >> 1) * HSBUF;
        bf16x8 af[3], bfr[8];
#pragma unroll
        for (int mf = 0; mf < 3; ++mf) {
            const int co = cobase + mf * 16 + ln;
            af[mf] = *(const bf16x8*)(pwb +
                ((unsigned)(co * PWROW + pair * 64 + kg * 16) ^
                 (unsigned)((co & 7) << 4)));
        }
#pragma unroll
        for (int nf = 0; nf < 8; ++nf) {
            const int pxv = pxbase + nf * 16 + ln;
            const unsigned boff = (unsigned)((pxv * HSROW + (kg & 1) * 16) ^
                                             (((pxv >> 2) & 7) << 4));
            bfr[nf] = *(const bf16x8*)(hsb + qbase + boff);
        }
#pragma unroll
        for (int mf = 0; mf < 3; ++mf)
#pragma unroll
            for (int nf = 0; nf < 8; ++nf)
                acc[mf][nf] = __builtin_amdgcn_mfma_f32_16x16x32_bf16(
                    af[mf], bfr[nf], acc[mf][nf], 0, 0, 0);
        if (pair < 2) __syncthreads();   // protect hs overwrite by next pair
    }

    // epilogue: bias + gate, coalesced 64B segments, 2 rows
#pragma unroll
    for (int mf = 0; mf < 3; ++mf) {
#pragma unroll
        for (int rr = 0; rr < 4; ++rr) {
            const int co = cobase + mf * 16 + kg * 4 + rr;
            const float bias = pw_b[e * DIM + co];
            float* obase = out + ((size_t)(b * DIM + co) * HH + r0) * WW;
#pragma unroll
            for (int nf = 0; nf < 8; ++nf) {
                const int pxv = pxbase + nf * 16 + ln;
                obase[(pxv >> 7) * WW + (pxv & 127)] = (acc[mf][nf][rr] + bias) * g;
            }
        }
    }
}

extern "C" void kernel_launch(void* const* d_in, const int* in_sizes, int n_in,
                              void* d_out, int out_size, void* d_ws, size_t ws_size,
                              hipStream_t stream) {
    const float* x    = (const float*)d_in[0];
    const float* dw_w = (const float*)d_in[1];
    const float* dw_b = (const float*)d_in[2];
    const float* pw_w = (const float*)d_in[3];
    const float* pw_b = (const float*)d_in[4];
    const float* rw   = (const float*)d_in[5];
    const float* rb   = (const float*)d_in[6];
    float* out = (float*)d_out;

    float* pooled = (float*)d_ws;              // B*C floats
    float* gate = pooled + BB * DIM;           // B floats
    int* sel = (int*)(gate + BB);              // B ints

    pool_kernel<<<BB * DIM, 256, 0, stream>>>(x, pooled);
    router_kernel<<<1, 64, 0, stream>>>(pooled, rw, rb, gate, sel);
    moe_main<<<(HH / 2) * BB, 256, 0, stream>>>(x, dw_w, dw_b, pw_w, pw_b,
                                                gate, sel, out);
}

// Round 10
// 81.520 us; speedup vs baseline: 1.3781x; 1.3781x over previous
//
#include <hip/hip_runtime.h>
#include <hip/hip_fp16.h>
#include <math.h>
#include <type_traits>

#define DIM 96
#define NE 4
#define HH 128
#define WW 128
#define BB 16
#define KP 24   // u16 per hs row: 48 B
#define HSROW (KP * 2)           // 48 B
#define HSBUF (WW * HSROW)       // 6144 B per sub-buffer
#define PWROW 192                // bytes per pwb row (96 k bf16)
#define XH_OFF 8192
#define XH_ELEMS ((size_t)BB * DIM * HH * WW)

typedef __attribute__((ext_vector_type(8))) __bf16 bf16x8;
typedef __attribute__((ext_vector_type(4))) float floatx4;

__device__ __forceinline__ unsigned short f2bf(float f) {
    unsigned u = __builtin_bit_cast(unsigned, f);
    unsigned r = u + 0x7FFFu + ((u >> 16) & 1u);   // RNE
    return (unsigned short)(r >> 16);
}
__device__ __forceinline__ unsigned pack2(float a, float b) {
    return (unsigned)f2bf(a) | ((unsigned)f2bf(b) << 16);
}
__device__ __forceinline__ float h2f(unsigned short u) {
    __half_raw hr; hr.x = u;
    return __half2float(__half(hr));
}
__device__ __forceinline__ unsigned short f2h(float f) {
    __half h = __float2half(f);
    return *(unsigned short*)&h;
}

// exact-erf GELU via Abramowitz-Stegun 7.1.26 (|eps| <= 1.5e-7), branchless
__device__ __forceinline__ float gelu_erf(float h) {
    const float x = h * 0.70710678118654752f;
    const float a = fabsf(x);
    const float t = __builtin_amdgcn_rcpf(__builtin_fmaf(0.3275911f, a, 1.0f));
    float p = __builtin_fmaf(1.061405429f, t, -1.453152027f);
    p = __builtin_fmaf(p, t, 1.421413741f);
    p = __builtin_fmaf(p, t, -0.284496736f);
    p = __builtin_fmaf(p, t, 0.254829592f);
    p *= t;
    const float e = __expf(-x * x);
    float erfv = __builtin_fmaf(-p, e, 1.0f);
    erfv = copysignf(erfv, x);
    return 0.5f * h * (1.0f + erfv);
}

// ---------------- Kernel A: per-(b,c) mean pool + fp16 x copy ----------------
__global__ __launch_bounds__(256) void pool_kernel(const float* __restrict__ x,
                                                   float* __restrict__ pooled,
                                                   unsigned short* __restrict__ xh) {
    const int bc = blockIdx.x;
    const float4* p = (const float4*)(x + (size_t)bc * (HH * WW));
    ushort4* q = (ushort4*)xh + (size_t)bc * (HH * WW / 4);
    const int t = threadIdx.x;
    float s = 0.f;
#pragma unroll
    for (int k = 0; k < (HH * WW / 4) / 256; ++k) {
        float4 v = p[t + k * 256];
        s += v.x + v.y + v.z + v.w;
        if (xh) {
            ushort4 o;
            o.x = f2h(v.x); o.y = f2h(v.y); o.z = f2h(v.z); o.w = f2h(v.w);
            q[t + k * 256] = o;
        }
    }
#pragma unroll
    for (int off = 32; off; off >>= 1) s += __shfl_down(s, off, 64);
    __shared__ float ls[4];
    if ((t & 63) == 0) ls[t >> 6] = s;
    __syncthreads();
    if (t == 0) pooled[bc] = (ls[0] + ls[1] + ls[2] + ls[3]) * (1.0f / (HH * WW));
}

// ---------------- Kernel B: router ----------------
__global__ void router_kernel(const float* __restrict__ pooled,
                              const float* __restrict__ rw,
                              const float* __restrict__ rb,
                              float* __restrict__ gate, int* __restrict__ sel) {
    const int b = threadIdx.x;
    if (b >= BB) return;
    float logits[NE];
#pragma unroll
    for (int e = 0; e < NE; ++e) {
        float s = rb[e];
        for (int c = 0; c < DIM; ++c) s += pooled[b * DIM + c] * rw[e * DIM + c];
        logits[e] = s;
    }
    float m = logits[0];
    int mi = 0;
#pragma unroll
    for (int e = 1; e < NE; ++e)
        if (logits[e] > m) { m = logits[e]; mi = e; }
    float denom = 0.f;
#pragma unroll
    for (int e = 0; e < NE; ++e) denom += expf(logits[e] - m);
    float w = 1.0f / denom;
    gate[b] = w / (w + 1e-8f);
    sel[b] = mi;
}

template <bool USEH>
using sub_t = typename std::conditional<USEH, ushort4, float4>::type;

template <bool USEH>
__device__ __forceinline__ float4 to_f4(sub_t<USEH> v) {
    if constexpr (USEH)
        return make_float4(h2f(v.x), h2f(v.y), h2f(v.z), h2f(v.w));
    else
        return v;
}

// issue 6 loads (2 ch x 3 rows) for one 16-ch sub-chunk
template <bool USEH, class T>
__device__ __forceinline__ void issue_sub(const T* __restrict__ x, int b,
                                          int cbase, int cg, int rr0, int r,
                                          int rr2, int p4, sub_t<USEH> f[2][3]) {
#pragma unroll
    for (int u = 0; u < 2; ++u) {
        const T* pl = x + (size_t)(b * DIM + cbase + cg * 2 + u) * (HH * WW);
        f[u][0] = *(const sub_t<USEH>*)(pl + rr0 * WW + p4);
        f[u][1] = *(const sub_t<USEH>*)(pl + r   * WW + p4);
        f[u][2] = *(const sub_t<USEH>*)(pl + rr2 * WW + p4);
    }
}

// depthwise taps + GELU from preloaded registers -> swizzled hs writes
template <bool USEH>
__device__ __forceinline__ void compute_sub(const sub_t<USEH> f[2][3],
                                            const float (*dwc)[12], int cb,
                                            int cg, float lmask, float rmask,
                                            unsigned char* hsbuf, int p4,
                                            unsigned swz) {
    float hq[2][4];
#pragma unroll
    for (int u = 0; u < 2; ++u) {
        const int c = cb + cg * 2 + u;
        const float4 wA = *(const float4*)&dwc[c][0];   // q0..q3
        const float4 wB = *(const float4*)&dwc[c][4];   // q4..q7
        const float4 wC = *(const float4*)&dwc[c][8];   // q8, bias
        float h0 = wC.y, h1 = wC.y, h2 = wC.y, h3 = wC.y;
#pragma unroll
        for (int row = 0; row < 3; ++row) {
            const float ta = (row == 0) ? wA.x : ((row == 1) ? wA.w : wB.z);
            const float tb = (row == 0) ? wA.y : ((row == 1) ? wB.x : wB.w);
            const float tc = (row == 0) ? wA.z : ((row == 1) ? wB.y : wC.x);
            const float4 f4 = to_f4<USEH>(f[u][row]);
            const float vl = __shfl_up(f4.w, 1, 32) * lmask;
            const float vr = __shfl_down(f4.x, 1, 32) * rmask;
            h0 = __builtin_fmaf(ta, vl,   __builtin_fmaf(tb, f4.x, __builtin_fmaf(tc, f4.y, h0)));
            h1 = __builtin_fmaf(ta, f4.x, __builtin_fmaf(tb, f4.y, __builtin_fmaf(tc, f4.z, h1)));
            h2 = __builtin_fmaf(ta, f4.y, __builtin_fmaf(tb, f4.z, __builtin_fmaf(tc, f4.w, h2)));
            h3 = __builtin_fmaf(ta, f4.z, __builtin_fmaf(tb, f4.w, __builtin_fmaf(tc, vr, h3)));
        }
        hq[u][0] = gelu_erf(h0);
        hq[u][1] = gelu_erf(h1);
        hq[u][2] = gelu_erf(h2);
        hq[u][3] = gelu_erf(h3);
    }
    const unsigned wb0 = (unsigned)(p4 * HSROW + cg * 4);
#pragma unroll
    for (int j = 0; j < 4; ++j) {
        const unsigned off = (wb0 + (unsigned)j * HSROW) ^ swz;
        *(unsigned*)(hsbuf + off) = pack2(hq[0][j], hq[1][j]);
    }
}

// ---------------- Kernel C: fused expert, 4 barriers total ----------------
// 256 threads = 4 waves, 1 row per block. pw^T staged once (XOR-swizzled);
// hs double-buffered across PAIRS -> one barrier per 32-ch pair (3 in loop).
// XCD row-band swizzle. USEH: x loads from the fp16 L3-resident copy.
template <bool USEH, class T>
__global__ __launch_bounds__(256, 3) void moe_main(
    const T* __restrict__ x, const float* __restrict__ dw_w,
    const float* __restrict__ dw_b, const float* __restrict__ pw_w,
    const float* __restrict__ pw_b, const float* __restrict__ gate,
    const int* __restrict__ sel, float* __restrict__ out) {
    __shared__ __align__(16) unsigned char pwb[DIM * PWROW];   // 18 KB
    __shared__ __align__(16) unsigned char hsb[4 * HSBUF];     // 24 KB
    __shared__ float dwc[DIM][12];                             // 4.6 KB

    const int t = threadIdx.x;
    const unsigned bid = blockIdx.x;
    const int xcd = bid & 7;
    const int s = bid >> 3;
    const int b = s & 15;              // b-fastest within an XCD's band
    const int r = xcd * 16 + (s >> 4); // 16-row band per XCD
    const int e = sel[b];
    const float g = gate[b];

    const int lane = t & 63, w = t >> 6;
    const int wm = w & 1, wn = w >> 1;
    const int ln = lane & 15, kg = lane >> 4;
    const int cobase = wm * 48, pxbase = wn * 64;

    const int g32 = t & 31;        // px group (4 px each)
    const int p4 = g32 * 4;
    const int cg = t >> 5;         // 0..7 channel group (2 ch each)
    const unsigned swz = (unsigned)((g32 & 7) << 4);
    const float lmask = (p4 == 0) ? 0.f : 1.f;
    const float rmask = (p4 == 124) ? 0.f : 1.f;

    const float m0 = (r > 0) ? 1.f : 0.f;
    const float m2 = (r < HH - 1) ? 1.f : 0.f;
    const int rr0 = (r > 0) ? r - 1 : 0;
    const int rr2 = (r < HH - 1) ? r + 1 : HH - 1;

    // prologue: issue pair-0 loads before any staging
    sub_t<USEH> fA[2][3], fB[2][3];
    issue_sub<USEH>(x, b, 0, cg, rr0, r, rr2, p4, fA);
    issue_sub<USEH>(x, b, 16, cg, rr0, r, rr2, p4, fB);

    // ---- stage pw^T once: [co][96 k] bf16, 192 B rows, XOR (co&7)<<4
#pragma unroll
    for (int i = 0; i < 18; ++i) {
        const int u = i * 256 + t;               // 0..4607 dword slots
        const int co = u / 48, kp = u - co * 48;
        const float2 v = *(const float2*)(pw_w +
            ((size_t)e * DIM + co) * DIM + kp * 2);
        *(unsigned*)(pwb + ((unsigned)(co * PWROW + kp * 4) ^
                            (unsigned)((co & 7) << 4))) = pack2(v.x, v.y);
    }
    // ---- stage depthwise taps + bias, row-edge masks folded in
    for (int j = t; j < DIM * 12; j += 256) {
        const int c = j / 12, q = j - c * 12;
        float v = 0.f;
        if (q < 9) {
            v = dw_w[((size_t)e * DIM + c) * 9 + q];
            if (q < 3) v *= m0;
            if (q >= 6) v *= m2;
        } else if (q == 9) v = dw_b[e * DIM + c];
        dwc[c][q] = v;
    }
    __syncthreads();

    floatx4 acc[3][4];
#pragma unroll
    for (int i = 0; i < 3; ++i)
#pragma unroll
        for (int j = 0; j < 4; ++j) acc[i][j] = (floatx4){0.f, 0.f, 0.f, 0.f};

#pragma unroll
    for (int pair = 0; pair < 3; ++pair) {
        const int cb = pair * 32;
        unsigned char* h0 = hsb + (unsigned)((pair & 1) * 2) * HSBUF;
        unsigned char* h1 = h0 + HSBUF;
        // compute sub0 from in-flight fA, refill fA for next pair
        compute_sub<USEH>(fA, dwc, cb, cg, lmask, rmask, h0, p4, swz);
        if (pair < 2) issue_sub<USEH>(x, b, cb + 32, cg, rr0, r, rr2, p4, fA);
        // compute sub1 from in-flight fB, refill fB for next pair
        compute_sub<USEH>(fB, dwc, cb + 16, cg, lmask, rmask, h1, p4, swz);
        if (pair < 2) issue_sub<USEH>(x, b, cb + 48, cg, rr0, r, rr2, p4, fB);
        __syncthreads();   // the only barrier in the pair

        // MFMA: K=32; kg>>1 picks sub-buffer, kg&1 picks 16B half-row
        const unsigned qbase = (unsigned)((pair & 1) * 2 + (kg >> 1)) * HSBUF;
        bf16x8 af[3], bfr[4];
#pragma unroll
        for (int mf = 0; mf < 3; ++mf) {
            const int co = cobase + mf * 16 + ln;
            af[mf] = *(const bf16x8*)(pwb +
                ((unsigned)(co * PWROW + pair * 64 + kg * 16) ^
                 (unsigned)((co & 7) << 4)));
        }
#pragma unroll
        for (int nf = 0; nf < 4; ++nf) {
            const int pxv = pxbase + nf * 16 + ln;
            const unsigned boff = (unsigned)((pxv * HSROW + (kg & 1) * 16) ^
                                             (((pxv >> 2) & 7) << 4));
            bfr[nf] = *(const bf16x8*)(hsb + qbase + boff);
        }
#pragma unroll
        for (int mf = 0; mf < 3; ++mf)
#pragma unroll
            for (int nf = 0; nf < 4; ++nf)
                acc[mf][nf] = __builtin_amdgcn_mfma_f32_16x16x32_bf16(
                    af[mf], bfr[nf], acc[mf][nf], 0, 0, 0);
        // no second barrier: next pair writes the OTHER hs buffers
    }

    // epilogue: bias + gate, coalesced 64B segments
#pragma unroll
    for (int mf = 0; mf < 3; ++mf) {
#pragma unroll
        for (int rr = 0; rr < 4; ++rr) {
            const int co = cobase + mf * 16 + kg * 4 + rr;
            const float bias = pw_b[e * DIM + co];
            float* orow = out + ((size_t)(b * DIM + co) * HH + r) * WW;
#pragma unroll
            for (int nf = 0; nf < 4; ++nf)
                orow[pxbase + nf * 16 + ln] = (acc[mf][nf][rr] + bias) * g;
        }
    }
}

extern "C" void kernel_launch(void* const* d_in, const int* in_sizes, int n_in,
                              void* d_out, int out_size, void* d_ws, size_t ws_size,
                              hipStream_t stream) {
    const float* x    = (const float*)d_in[0];
    const float* dw_w = (const float*)d_in[1];
    const float* dw_b = (const float*)d_in[2];
    const float* pw_w = (const float*)d_in[3];
    const float* pw_b = (const float*)d_in[4];
    const float* rw   = (const float*)d_in[5];
    const float* rb   = (const float*)d_in[6];
    float* out = (float*)d_out;

    float* pooled = (float*)d_ws;              // B*C floats
    float* gate = pooled + BB * DIM;           // B floats
    int* sel = (int*)(gate + BB);              // B ints
    const bool useh = ws_size >= (size_t)XH_OFF + XH_ELEMS * 2;
    unsigned short* xh = (unsigned short*)((char*)d_ws + XH_OFF);

    pool_kernel<<<BB * DIM, 256, 0, stream>>>(x, pooled, useh ? xh : nullptr);
    router_kernel<<<1, 64, 0, stream>>>(pooled, rw, rb, gate, sel);
    if (useh)
        moe_main<true><<<HH * BB, 256, 0, stream>>>(xh, dw_w, dw_b, pw_w, pw_b,
                                                    gate, sel, out);
    else
        moe_main<false><<<HH * BB, 256, 0, stream>>>(x, dw_w, dw_b, pw_w, pw_b,
                                                     gate, sel, out);
}

// Round 11
// 76.764 us; speedup vs baseline: 1.4634x; 1.0620x over previous
//
#include <hip/hip_runtime.h>
#include <math.h>

#define DIM 96
#define NE 4
#define HH 128
#define WW 128
#define BB 16
#define KP 24   // u16 per hs row: 48 B
#define HSROW (KP * 2)           // 48 B
#define HSBUF (WW * HSROW)       // 6144 B per sub-buffer
#define PWROW 192                // bytes per pwb row (96 k bf16)

typedef __attribute__((ext_vector_type(8))) __bf16 bf16x8;
typedef __attribute__((ext_vector_type(4))) float floatx4;

__device__ __forceinline__ unsigned short f2bf(float f) {
    unsigned u = __builtin_bit_cast(unsigned, f);
    unsigned r = u + 0x7FFFu + ((u >> 16) & 1u);   // RNE
    return (unsigned short)(r >> 16);
}
__device__ __forceinline__ unsigned pack2(float a, float b) {
    return (unsigned)f2bf(a) | ((unsigned)f2bf(b) << 16);
}

// LDS-only barrier: make ds_writes visible, rendezvous, but do NOT drain
// vmcnt -- in-flight global prefetches survive the barrier (T4 pattern).
__device__ __forceinline__ void barrier_lds_only() {
    asm volatile("s_waitcnt lgkmcnt(0)" ::: "memory");
    __builtin_amdgcn_s_barrier();
}

// exact-erf GELU via Abramowitz-Stegun 7.1.26 (|eps| <= 1.5e-7), branchless
__device__ __forceinline__ float gelu_erf(float h) {
    const float x = h * 0.70710678118654752f;
    const float a = fabsf(x);
    const float t = __builtin_amdgcn_rcpf(__builtin_fmaf(0.3275911f, a, 1.0f));
    float p = __builtin_fmaf(1.061405429f, t, -1.453152027f);
    p = __builtin_fmaf(p, t, 1.421413741f);
    p = __builtin_fmaf(p, t, -0.284496736f);
    p = __builtin_fmaf(p, t, 0.254829592f);
    p *= t;
    const float e = __expf(-x * x);
    float erfv = __builtin_fmaf(-p, e, 1.0f);
    erfv = copysignf(erfv, x);
    return 0.5f * h * (1.0f + erfv);
}

// ---------------- Kernel A: per-(b,c) mean pool ----------------
__global__ __launch_bounds__(256) void pool_kernel(const float* __restrict__ x,
                                                   float* __restrict__ pooled) {
    const int bc = blockIdx.x;
    const float4* p = (const float4*)(x + (size_t)bc * (HH * WW));
    const int t = threadIdx.x;
    float s = 0.f;
#pragma unroll
    for (int k = 0; k < (HH * WW / 4) / 256; ++k) {
        float4 v = p[t + k * 256];
        s += v.x + v.y + v.z + v.w;
    }
#pragma unroll
    for (int off = 32; off; off >>= 1) s += __shfl_down(s, off, 64);
    __shared__ float ls[4];
    if ((t & 63) == 0) ls[t >> 6] = s;
    __syncthreads();
    if (t == 0) pooled[bc] = (ls[0] + ls[1] + ls[2] + ls[3]) * (1.0f / (HH * WW));
}

// ---------------- Kernel B: router ----------------
__global__ void router_kernel(const float* __restrict__ pooled,
                              const float* __restrict__ rw,
                              const float* __restrict__ rb,
                              float* __restrict__ gate, int* __restrict__ sel) {
    const int b = threadIdx.x;
    if (b >= BB) return;
    float logits[NE];
#pragma unroll
    for (int e = 0; e < NE; ++e) {
        float s = rb[e];
        for (int c = 0; c < DIM; ++c) s += pooled[b * DIM + c] * rw[e * DIM + c];
        logits[e] = s;
    }
    float m = logits[0];
    int mi = 0;
#pragma unroll
    for (int e = 1; e < NE; ++e)
        if (logits[e] > m) { m = logits[e]; mi = e; }
    float denom = 0.f;
#pragma unroll
    for (int e = 0; e < NE; ++e) denom += expf(logits[e] - m);
    float w = 1.0f / denom;
    gate[b] = w / (w + 1e-8f);
    sel[b] = mi;
}

// issue 6 float4 loads (2 ch x 3 rows) for one 16-ch sub-chunk
__device__ __forceinline__ void issue_sub(const float* __restrict__ x, int b,
                                          int cbase, int cg, int rr0, int r,
                                          int rr2, int p4, float4 f[2][3]) {
#pragma unroll
    for (int u = 0; u < 2; ++u) {
        const float* pl = x + (size_t)(b * DIM + cbase + cg * 2 + u) * (HH * WW);
        f[u][0] = *(const float4*)(pl + rr0 * WW + p4);
        f[u][1] = *(const float4*)(pl + r   * WW + p4);
        f[u][2] = *(const float4*)(pl + rr2 * WW + p4);
    }
}

// depthwise taps + GELU from preloaded registers -> swizzled hs writes
__device__ __forceinline__ void compute_sub(const float4 f[2][3],
                                            const float (*dwc)[12], int cb,
                                            int cg, float lmask, float rmask,
                                            unsigned char* hsbuf, int p4,
                                            unsigned swz) {
    float hq[2][4];
#pragma unroll
    for (int u = 0; u < 2; ++u) {
        const int c = cb + cg * 2 + u;
        const float4 wA = *(const float4*)&dwc[c][0];   // q0..q3
        const float4 wB = *(const float4*)&dwc[c][4];   // q4..q7
        const float4 wC = *(const float4*)&dwc[c][8];   // q8, bias
        float h0 = wC.y, h1 = wC.y, h2 = wC.y, h3 = wC.y;
#pragma unroll
        for (int row = 0; row < 3; ++row) {
            const float ta = (row == 0) ? wA.x : ((row == 1) ? wA.w : wB.z);
            const float tb = (row == 0) ? wA.y : ((row == 1) ? wB.x : wB.w);
            const float tc = (row == 0) ? wA.z : ((row == 1) ? wB.y : wC.x);
            const float4 f4 = f[u][row];
            const float vl = __shfl_up(f4.w, 1, 32) * lmask;
            const float vr = __shfl_down(f4.x, 1, 32) * rmask;
            h0 = __builtin_fmaf(ta, vl,   __builtin_fmaf(tb, f4.x, __builtin_fmaf(tc, f4.y, h0)));
            h1 = __builtin_fmaf(ta, f4.x, __builtin_fmaf(tb, f4.y, __builtin_fmaf(tc, f4.z, h1)));
            h2 = __builtin_fmaf(ta, f4.y, __builtin_fmaf(tb, f4.z, __builtin_fmaf(tc, f4.w, h2)));
            h3 = __builtin_fmaf(ta, f4.z, __builtin_fmaf(tb, f4.w, __builtin_fmaf(tc, vr, h3)));
        }
        hq[u][0] = gelu_erf(h0);
        hq[u][1] = gelu_erf(h1);
        hq[u][2] = gelu_erf(h2);
        hq[u][3] = gelu_erf(h3);
    }
    const unsigned wb0 = (unsigned)(p4 * HSROW + cg * 4);
#pragma unroll
    for (int j = 0; j < 4; ++j) {
        const unsigned off = (wb0 + (unsigned)j * HSROW) ^ swz;
        *(unsigned*)(hsbuf + off) = pack2(hq[0][j], hq[1][j]);
    }
}

// ---------------- Kernel C: fused expert, lgkm-only barriers ----------------
// 256 threads = 4 waves, 1 row per block. pw^T staged once (XOR-swizzled);
// hs double-buffered across PAIRS -> one lgkm-only barrier per 32-ch pair.
// Global prefetches for pair p+1 stay in flight ACROSS the barrier (no vmcnt
// drain). XCD row-band swizzle for halo L2 locality.
__global__ __launch_bounds__(256, 3) void moe_main(
    const float* __restrict__ x, const float* __restrict__ dw_w,
    const float* __restrict__ dw_b, const float* __restrict__ pw_w,
    const float* __restrict__ pw_b, const float* __restrict__ gate,
    const int* __restrict__ sel, float* __restrict__ out) {
    __shared__ __align__(16) unsigned char pwb[DIM * PWROW];   // 18 KB
    __shared__ __align__(16) unsigned char hsb[4 * HSBUF];     // 24 KB
    __shared__ float dwc[DIM][12];                             // 4.6 KB

    const int t = threadIdx.x;
    const unsigned bid = blockIdx.x;
    const int xcd = bid & 7;
    const int s = bid >> 3;
    const int b = s & 15;              // b-fastest within an XCD's band
    const int r = xcd * 16 + (s >> 4); // 16-row band per XCD
    const int e = sel[b];
    const float g = gate[b];

    const int lane = t & 63, w = t >> 6;
    const int wm = w & 1, wn = w >> 1;
    const int ln = lane & 15, kg = lane >> 4;
    const int cobase = wm * 48, pxbase = wn * 64;

    const int g32 = t & 31;        // px group (4 px each)
    const int p4 = g32 * 4;
    const int cg = t >> 5;         // 0..7 channel group (2 ch each)
    const unsigned swz = (unsigned)((g32 & 7) << 4);
    const float lmask = (p4 == 0) ? 0.f : 1.f;
    const float rmask = (p4 == 124) ? 0.f : 1.f;

    const float m0 = (r > 0) ? 1.f : 0.f;
    const float m2 = (r < HH - 1) ? 1.f : 0.f;
    const int rr0 = (r > 0) ? r - 1 : 0;
    const int rr2 = (r < HH - 1) ? r + 1 : HH - 1;

    // prologue: issue pair-0 loads before any staging
    float4 fA[2][3], fB[2][3];
    issue_sub(x, b, 0, cg, rr0, r, rr2, p4, fA);
    issue_sub(x, b, 16, cg, rr0, r, rr2, p4, fB);

    // ---- stage pw^T once: [co][96 k] bf16, 192 B rows, XOR (co&7)<<4
#pragma unroll
    for (int i = 0; i < 18; ++i) {
        const int u = i * 256 + t;               // 0..4607 dword slots
        const int co = u / 48, kp = u - co * 48;
        const float2 v = *(const float2*)(pw_w +
            ((size_t)e * DIM + co) * DIM + kp * 2);
        *(unsigned*)(pwb + ((unsigned)(co * PWROW + kp * 4) ^
                            (unsigned)((co & 7) << 4))) = pack2(v.x, v.y);
    }
    // ---- stage depthwise taps + bias, row-edge masks folded in
    for (int j = t; j < DIM * 12; j += 256) {
        const int c = j / 12, q = j - c * 12;
        float v = 0.f;
        if (q < 9) {
            v = dw_w[((size_t)e * DIM + c) * 9 + q];
            if (q < 3) v *= m0;
            if (q >= 6) v *= m2;
        } else if (q == 9) v = dw_b[e * DIM + c];
        dwc[c][q] = v;
    }
    barrier_lds_only();   // fA/fB prefetches survive

    floatx4 acc[3][4];
#pragma unroll
    for (int i = 0; i < 3; ++i)
#pragma unroll
        for (int j = 0; j < 4; ++j) acc[i][j] = (floatx4){0.f, 0.f, 0.f, 0.f};

#pragma unroll
    for (int pair = 0; pair < 3; ++pair) {
        const int cb = pair * 32;
        unsigned char* h0 = hsb + (unsigned)((pair & 1) * 2) * HSBUF;
        unsigned char* h1 = h0 + HSBUF;
        // compute sub0 from in-flight fA, refill fA for next pair
        compute_sub(fA, dwc, cb, cg, lmask, rmask, h0, p4, swz);
        if (pair < 2) issue_sub(x, b, cb + 32, cg, rr0, r, rr2, p4, fA);
        // compute sub1 from in-flight fB, refill fB for next pair
        compute_sub(fB, dwc, cb + 16, cg, lmask, rmask, h1, p4, swz);
        if (pair < 2) issue_sub(x, b, cb + 48, cg, rr0, r, rr2, p4, fB);
        barrier_lds_only();   // hs visible; next-pair loads stay in flight

        // MFMA: K=32; kg>>1 picks sub-buffer, kg&1 picks 16B half-row
        const unsigned qbase = (unsigned)((pair & 1) * 2 + (kg >> 1)) * HSBUF;
        bf16x8 af[3], bfr[4];
#pragma unroll
        for (int mf = 0; mf < 3; ++mf) {
            const int co = cobase + mf * 16 + ln;
            af[mf] = *(const bf16x8*)(pwb +
                ((unsigned)(co * PWROW + pair * 64 + kg * 16) ^
                 (unsigned)((co & 7) << 4)));
        }
#pragma unroll
        for (int nf = 0; nf < 4; ++nf) {
            const int pxv = pxbase + nf * 16 + ln;
            const unsigned boff = (unsigned)((pxv * HSROW + (kg & 1) * 16) ^
                                             (((pxv >> 2) & 7) << 4));
            bfr[nf] = *(const bf16x8*)(hsb + qbase + boff);
        }
#pragma unroll
        for (int mf = 0; mf < 3; ++mf)
#pragma unroll
            for (int nf = 0; nf < 4; ++nf)
                acc[mf][nf] = __builtin_amdgcn_mfma_f32_16x16x32_bf16(
                    af[mf], bfr[nf], acc[mf][nf], 0, 0, 0);
        // no second barrier: next pair writes the OTHER hs buffers
    }

    // epilogue: bias + gate, coalesced 64B segments
#pragma unroll
    for (int mf = 0; mf < 3; ++mf) {
#pragma unroll
        for (int rr = 0; rr < 4; ++rr) {
            const int co = cobase + mf * 16 + kg * 4 + rr;
            const float bias = pw_b[e * DIM + co];
            float* orow = out + ((size_t)(b * DIM + co) * HH + r) * WW;
#pragma unroll
            for (int nf = 0; nf < 4; ++nf)
                orow[pxbase + nf * 16 + ln] = (acc[mf][nf][rr] + bias) * g;
        }
    }
}

extern "C" void kernel_launch(void* const* d_in, const int* in_sizes, int n_in,
                              void* d_out, int out_size, void* d_ws, size_t ws_size,
                              hipStream_t stream) {
    const float* x    = (const float*)d_in[0];
    const float* dw_w = (const float*)d_in[1];
    const float* dw_b = (const float*)d_in[2];
    const float* pw_w = (const float*)d_in[3];
    const float* pw_b = (const float*)d_in[4];
    const float* rw   = (const float*)d_in[5];
    const float* rb   = (const float*)d_in[6];
    float* out = (float*)d_out;

    float* pooled = (float*)d_ws;              // B*C floats
    float* gate = pooled + BB * DIM;           // B floats
    int* sel = (int*)(gate + BB);              // B ints

    pool_kernel<<<BB * DIM, 256, 0, stream>>>(x, pooled);
    router_kernel<<<1, 64, 0, stream>>>(pooled, rw, rb, gate, sel);
    moe_main<<<HH * BB, 256, 0, stream>>>(x, dw_w, dw_b, pw_w, pw_b, gate, sel, out);
}

// Round 12
// 67.223 us; speedup vs baseline: 1.6711x; 1.1419x over previous
//
#include <hip/hip_runtime.h>
#include <math.h>

#define DIM 96
#define NE 4
#define HH 128
#define WW 128
#define BB 16
#define KP 24   // u16 per hs row: 48 B
#define HSROW (KP * 2)           // 48 B
#define HSBUF (WW * HSROW)       // 6144 B per sub-buffer
#define PWROW 192                // bytes per pwb row (96 k bf16)

typedef __attribute__((ext_vector_type(8))) __bf16 bf16x8;
typedef __attribute__((ext_vector_type(4))) float floatx4;

__device__ __forceinline__ unsigned short f2bf(float f) {
    unsigned u = __builtin_bit_cast(unsigned, f);
    unsigned r = u + 0x7FFFu + ((u >> 16) & 1u);   // RNE
    return (unsigned short)(r >> 16);
}
__device__ __forceinline__ unsigned pack2(float a, float b) {
    return (unsigned)f2bf(a) | ((unsigned)f2bf(b) << 16);
}

// LDS-only barrier: make ds_writes visible, rendezvous, but do NOT drain
// vmcnt -- in-flight global prefetches survive the barrier (T4 pattern).
__device__ __forceinline__ void barrier_lds_only() {
    asm volatile("s_waitcnt lgkmcnt(0)" ::: "memory");
    __builtin_amdgcn_s_barrier();
}

// exact-erf GELU via Abramowitz-Stegun 7.1.26 (|eps| <= 1.5e-7), branchless
__device__ __forceinline__ float gelu_erf(float h) {
    const float x = h * 0.70710678118654752f;
    const float a = fabsf(x);
    const float t = __builtin_amdgcn_rcpf(__builtin_fmaf(0.3275911f, a, 1.0f));
    float p = __builtin_fmaf(1.061405429f, t, -1.453152027f);
    p = __builtin_fmaf(p, t, 1.421413741f);
    p = __builtin_fmaf(p, t, -0.284496736f);
    p = __builtin_fmaf(p, t, 0.254829592f);
    p *= t;
    const float e = __expf(-x * x);
    float erfv = __builtin_fmaf(-p, e, 1.0f);
    erfv = copysignf(erfv, x);
    return 0.5f * h * (1.0f + erfv);
}

// ---------------- Kernel A: per-(b,c) mean pool ----------------
__global__ __launch_bounds__(256) void pool_kernel(const float* __restrict__ x,
                                                   float* __restrict__ pooled) {
    const int bc = blockIdx.x;
    const float4* p = (const float4*)(x + (size_t)bc * (HH * WW));
    const int t = threadIdx.x;
    float s = 0.f;
#pragma unroll
    for (int k = 0; k < (HH * WW / 4) / 256; ++k) {
        float4 v = p[t + k * 256];
        s += v.x + v.y + v.z + v.w;
    }
#pragma unroll
    for (int off = 32; off; off >>= 1) s += __shfl_down(s, off, 64);
    __shared__ float ls[4];
    if ((t & 63) == 0) ls[t >> 6] = s;
    __syncthreads();
    if (t == 0) pooled[bc] = (ls[0] + ls[1] + ls[2] + ls[3]) * (1.0f / (HH * WW));
}

// issue 6 float4 loads (2 ch x 3 rows) for one 16-ch sub-chunk
__device__ __forceinline__ void issue_sub(const float* __restrict__ x, int b,
                                          int cbase, int cg, int rr0, int r,
                                          int rr2, int p4, float4 f[2][3]) {
#pragma unroll
    for (int u = 0; u < 2; ++u) {
        const float* pl = x + (size_t)(b * DIM + cbase + cg * 2 + u) * (HH * WW);
        f[u][0] = *(const float4*)(pl + rr0 * WW + p4);
        f[u][1] = *(const float4*)(pl + r   * WW + p4);
        f[u][2] = *(const float4*)(pl + rr2 * WW + p4);
    }
}

// depthwise taps + GELU from preloaded registers -> swizzled hs writes
__device__ __forceinline__ void compute_sub(const float4 f[2][3],
                                            const float (*dwc)[12], int cb,
                                            int cg, float lmask, float rmask,
                                            unsigned char* hsbuf, int p4,
                                            unsigned swz) {
    float hq[2][4];
#pragma unroll
    for (int u = 0; u < 2; ++u) {
        const int c = cb + cg * 2 + u;
        const float4 wA = *(const float4*)&dwc[c][0];   // q0..q3
        const float4 wB = *(const float4*)&dwc[c][4];   // q4..q7
        const float4 wC = *(const float4*)&dwc[c][8];   // q8, bias
        float h0 = wC.y, h1 = wC.y, h2 = wC.y, h3 = wC.y;
#pragma unroll
        for (int row = 0; row < 3; ++row) {
            const float ta = (row == 0) ? wA.x : ((row == 1) ? wA.w : wB.z);
            const float tb = (row == 0) ? wA.y : ((row == 1) ? wB.x : wB.w);
            const float tc = (row == 0) ? wA.z : ((row == 1) ? wB.y : wC.x);
            const float4 f4 = f[u][row];
            const float vl = __shfl_up(f4.w, 1, 32) * lmask;
            const float vr = __shfl_down(f4.x, 1, 32) * rmask;
            h0 = __builtin_fmaf(ta, vl,   __builtin_fmaf(tb, f4.x, __builtin_fmaf(tc, f4.y, h0)));
            h1 = __builtin_fmaf(ta, f4.x, __builtin_fmaf(tb, f4.y, __builtin_fmaf(tc, f4.z, h1)));
            h2 = __builtin_fmaf(ta, f4.y, __builtin_fmaf(tb, f4.z, __builtin_fmaf(tc, f4.w, h2)));
            h3 = __builtin_fmaf(ta, f4.z, __builtin_fmaf(tb, f4.w, __builtin_fmaf(tc, vr, h3)));
        }
        hq[u][0] = gelu_erf(h0);
        hq[u][1] = gelu_erf(h1);
        hq[u][2] = gelu_erf(h2);
        hq[u][3] = gelu_erf(h3);
    }
    const unsigned wb0 = (unsigned)(p4 * HSROW + cg * 4);
#pragma unroll
    for (int j = 0; j < 4; ++j) {
        const unsigned off = (wb0 + (unsigned)j * HSROW) ^ swz;
        *(unsigned*)(hsbuf + off) = pack2(hq[0][j], hq[1][j]);
    }
}

// ---------------- Kernel C: fused router + expert ----------------
// 256 threads = 4 waves, 1 row per block. Router computed in-prologue (wave w
// = expert w logit, shfl-reduced). pw^T staged once (XOR-swizzled); hs
// double-buffered across PAIRS; lgkm-only barriers. Row-fastest XCD mapping:
// each XCD owns 2 images with sequential rows -> halo reads are L2 hits.
__global__ __launch_bounds__(256, 3) void moe_main(
    const float* __restrict__ x, const float* __restrict__ dw_w,
    const float* __restrict__ dw_b, const float* __restrict__ pw_w,
    const float* __restrict__ pw_b, const float* __restrict__ pooled,
    const float* __restrict__ rw, const float* __restrict__ rb,
    float* __restrict__ out) {
    __shared__ __align__(16) unsigned char pwb[DIM * PWROW];   // 18 KB
    __shared__ __align__(16) unsigned char hsb[4 * HSBUF];     // 24 KB
    __shared__ float dwc[DIM][12];                             // 4.6 KB
    __shared__ float lsm[4];                                   // router logits

    const int t = threadIdx.x;
    const unsigned bid = blockIdx.x;      // 0..2047
    const int xcd = bid & 7;
    const int s = bid >> 3;               // 0..255
    const int b = xcd * 2 + (s >> 7);     // 2 images per XCD
    const int r = s & 127;                // rows sequential within XCD

    const int lane = t & 63, w = t >> 6;
    const int wm = w & 1, wn = w >> 1;
    const int ln = lane & 15, kg = lane >> 4;
    const int cobase = wm * 48, pxbase = wn * 64;

    const int g32 = t & 31;        // px group (4 px each)
    const int p4 = g32 * 4;
    const int cg = t >> 5;         // 0..7 channel group (2 ch each)
    const unsigned swz = (unsigned)((g32 & 7) << 4);
    const float lmask = (p4 == 0) ? 0.f : 1.f;
    const float rmask = (p4 == 124) ? 0.f : 1.f;

    const float m0 = (r > 0) ? 1.f : 0.f;
    const float m2 = (r < HH - 1) ? 1.f : 0.f;
    const int rr0 = (r > 0) ? r - 1 : 0;
    const int rr2 = (r < HH - 1) ? r + 1 : HH - 1;

    // prologue: issue pair-0 x prefetch (expert-independent) first
    float4 fA[2][3], fB[2][3];
    issue_sub(x, b, 0, cg, rr0, r, rr2, p4, fA);
    issue_sub(x, b, 16, cg, rr0, r, rr2, p4, fB);

    // ---- fused router: wave w computes expert w's logit
    {
        float part = pooled[b * DIM + lane] * rw[w * DIM + lane];
        if (lane < 32)
            part += pooled[b * DIM + 64 + lane] * rw[w * DIM + 64 + lane];
#pragma unroll
        for (int off = 32; off; off >>= 1) part += __shfl_down(part, off, 64);
        if (lane == 0) lsm[w] = part + rb[w];
    }
    barrier_lds_only();
    int e;
    float g;
    {
        const float l0 = lsm[0], l1 = lsm[1], l2 = lsm[2], l3 = lsm[3];
        float m = l0; int mi = 0;
        if (l1 > m) { m = l1; mi = 1; }
        if (l2 > m) { m = l2; mi = 2; }
        if (l3 > m) { m = l3; mi = 3; }
        const float denom = __expf(l0 - m) + __expf(l1 - m) +
                            __expf(l2 - m) + __expf(l3 - m);
        const float wv = 1.0f / denom;
        g = wv / (wv + 1e-8f);
        e = mi;
    }

    // ---- stage pw^T once: [co][96 k] bf16, 192 B rows, XOR (co&7)<<4
#pragma unroll
    for (int i = 0; i < 18; ++i) {
        const int u = i * 256 + t;               // 0..4607 dword slots
        const int co = u / 48, kp = u - co * 48;
        const float2 v = *(const float2*)(pw_w +
            ((size_t)e * DIM + co) * DIM + kp * 2);
        *(unsigned*)(pwb + ((unsigned)(co * PWROW + kp * 4) ^
                            (unsigned)((co & 7) << 4))) = pack2(v.x, v.y);
    }
    // ---- stage depthwise taps + bias, row-edge masks folded in
    for (int j = t; j < DIM * 12; j += 256) {
        const int c = j / 12, q = j - c * 12;
        float v = 0.f;
        if (q < 9) {
            v = dw_w[((size_t)e * DIM + c) * 9 + q];
            if (q < 3) v *= m0;
            if (q >= 6) v *= m2;
        } else if (q == 9) v = dw_b[e * DIM + c];
        dwc[c][q] = v;
    }
    barrier_lds_only();   // fA/fB prefetches survive

    floatx4 acc[3][4];
#pragma unroll
    for (int i = 0; i < 3; ++i)
#pragma unroll
        for (int j = 0; j < 4; ++j) acc[i][j] = (floatx4){0.f, 0.f, 0.f, 0.f};

#pragma unroll
    for (int pair = 0; pair < 3; ++pair) {
        const int cb = pair * 32;
        unsigned char* h0 = hsb + (unsigned)((pair & 1) * 2) * HSBUF;
        unsigned char* h1 = h0 + HSBUF;
        // compute sub0 from in-flight fA, refill fA for next pair
        compute_sub(fA, dwc, cb, cg, lmask, rmask, h0, p4, swz);
        if (pair < 2) issue_sub(x, b, cb + 32, cg, rr0, r, rr2, p4, fA);
        // compute sub1 from in-flight fB, refill fB for next pair
        compute_sub(fB, dwc, cb + 16, cg, lmask, rmask, h1, p4, swz);
        if (pair < 2) issue_sub(x, b, cb + 48, cg, rr0, r, rr2, p4, fB);
        barrier_lds_only();   // hs visible; next-pair loads stay in flight

        // MFMA: K=32; kg>>1 picks sub-buffer, kg&1 picks 16B half-row
        const unsigned qbase = (unsigned)((pair & 1) * 2 + (kg >> 1)) * HSBUF;
        bf16x8 af[3], bfr[4];
#pragma unroll
        for (int mf = 0; mf < 3; ++mf) {
            const int co = cobase + mf * 16 + ln;
            af[mf] = *(const bf16x8*)(pwb +
                ((unsigned)(co * PWROW + pair * 64 + kg * 16) ^
                 (unsigned)((co & 7) << 4)));
        }
#pragma unroll
        for (int nf = 0; nf < 4; ++nf) {
            const int pxv = pxbase + nf * 16 + ln;
            const unsigned boff = (unsigned)((pxv * HSROW + (kg & 1) * 16) ^
                                             (((pxv >> 2) & 7) << 4));
            bfr[nf] = *(const bf16x8*)(hsb + qbase + boff);
        }
#pragma unroll
        for (int mf = 0; mf < 3; ++mf)
#pragma unroll
            for (int nf = 0; nf < 4; ++nf)
                acc[mf][nf] = __builtin_amdgcn_mfma_f32_16x16x32_bf16(
                    af[mf], bfr[nf], acc[mf][nf], 0, 0, 0);
        // no second barrier: next pair writes the OTHER hs buffers
    }

    // epilogue: bias + gate, coalesced 64B segments
#pragma unroll
    for (int mf = 0; mf < 3; ++mf) {
#pragma unroll
        for (int rr = 0; rr < 4; ++rr) {
            const int co = cobase + mf * 16 + kg * 4 + rr;
            const float bias = pw_b[e * DIM + co];
            float* orow = out + ((size_t)(b * DIM + co) * HH + r) * WW;
#pragma unroll
            for (int nf = 0; nf < 4; ++nf)
                orow[pxbase + nf * 16 + ln] = (acc[mf][nf][rr] + bias) * g;
        }
    }
}

extern "C" void kernel_launch(void* const* d_in, const int* in_sizes, int n_in,
                              void* d_out, int out_size, void* d_ws, size_t ws_size,
                              hipStream_t stream) {
    const float* x    = (const float*)d_in[0];
    const float* dw_w = (const float*)d_in[1];
    const float* dw_b = (const float*)d_in[2];
    const float* pw_w = (const float*)d_in[3];
    const float* pw_b = (const float*)d_in[4];
    const float* rw   = (const float*)d_in[5];
    const float* rb   = (const float*)d_in[6];
    float* out = (float*)d_out;

    float* pooled = (float*)d_ws;              // B*C floats

    pool_kernel<<<BB * DIM, 256, 0, stream>>>(x, pooled);
    moe_main<<<HH * BB, 256, 0, stream>>>(x, dw_w, dw_b, pw_w, pw_b,
                                          pooled, rw, rb, out);
}